// Round 22
// baseline (477.485 us; speedup 1.0000x reference)
//
#include <hip/hip_runtime.h>
#include <stdint.h>

// Problem constants (fixed instance from setup_inputs)
#define B_   2
#define T_   64
#define S_   1024
#define C_   512
#define H_   8
#define N_   (T_ * S_)      // 65536
#define M_   (B_ * N_)      // 131072
#define WIN_ 5

typedef unsigned short u16;
typedef __bf16 bf16;
typedef __bf16 bf16x8 __attribute__((ext_vector_type(8)));
typedef float  f32x4  __attribute__((ext_vector_type(4)));
typedef u16    u16x8  __attribute__((ext_vector_type(8)));

static __device__ __forceinline__ u16 f2bf(float f) {
    return __builtin_bit_cast(u16, (bf16)f);   // RNE
}
static __device__ __forceinline__ float bf2f(u16 u) {
    return __builtin_bit_cast(float, (uint32_t)u << 16);
}
// async global->LDS, 16B per lane; LDS dest is wave-uniform base + lane*16
static __device__ __forceinline__ void gload16(const void* g, void* l) {
    __builtin_amdgcn_global_load_lds(
        (const __attribute__((address_space(1))) void*)g,
        (__attribute__((address_space(3))) void*)l, 16, 0, 0);
}
// row permutation: logical (b,t,s) flat row -> physical (b,s,t) flat row
static __device__ __forceinline__ long permute_row(long grow) {
    int b = (int)(grow >> 16);
    int t = (int)(grow >> 10) & 63;
    int s = (int)grow & 1023;
    return ((long)((b << 10) | s)) * 64 + t;
}

// Pre-swizzle layout (bf16 [row][512] operands): logical (chunk c in [0,16),
// granule g in [0,4), elem j) stored at
// r*512 + (c ^ ((rl>>3)&1))*32 + ((g ^ ((rl>>1)&3))<<3) + j,
// keys from the TILE-LOCAL row rl. 0 conflicts measured.

// ---------------------------------------------------------------------------
// Wout prep: W [512][512] fp32 -> WT [512][512] bf16, pre-swizzled.
// ---------------------------------------------------------------------------
__global__ __launch_bounds__(256) void prep_w(const float* __restrict__ W,
                                              u16* __restrict__ WT, int NCOL) {
    int id = blockIdx.x * 256 + threadIdx.x;
    int n  = id % NCOL;
    int gi = id / NCOL;
    int chunk = gi >> 2;
    int g     = gi & 3;
    int k0 = chunk * 32 + g * 8;
    int cs = chunk ^ ((n >> 3) & 1);
    int gs = g ^ ((n >> 1) & 3);
    u16x8 w;
    #pragma unroll
    for (int j = 0; j < 8; ++j) w[j] = f2bf(W[(size_t)(k0 + j) * NCOL + n]);
    *(u16x8*)&WT[(size_t)n * 512 + cs * 32 + gs * 8] = w;
}

// ---------------------------------------------------------------------------
// Wqkv prep, head-grouped: W [512][1536] fp32, col n = which*512 + h*64 + d
// -> WT2 row n' = h*192 + which*64 + d, bf16, pre-swizzled with keys from the
// PANEL-LOCAL row which*64+d.
// ---------------------------------------------------------------------------
__global__ __launch_bounds__(256) void prep_w2(const float* __restrict__ W,
                                               u16* __restrict__ WT2) {
    int id = blockIdx.x * 256 + threadIdx.x;
    int n  = id % 1536;
    int gi = id / 1536;
    int chunk = gi >> 2;
    int g     = gi & 3;
    int k0 = chunk * 32 + g * 8;
    int which = n >> 9;
    int h     = (n >> 6) & 7;
    int d     = n & 63;
    int rloc  = which * 64 + d;          // 0..191 panel-local row
    long np   = h * 192 + rloc;
    int cs = chunk ^ ((rloc >> 3) & 1);
    int gs = g ^ ((rloc >> 1) & 3);
    u16x8 w;
    #pragma unroll
    for (int j = 0; j < 8; ++j) w[j] = f2bf(W[(size_t)(k0 + j) * 1536 + n]);
    *(u16x8*)&WT2[(size_t)np * 512 + cs * 32 + gs * 8] = w;
}

// ---------------------------------------------------------------------------
// x prep: x [M][512] fp32 (rows (b,t,s)) -> xb bf16 rows PERMUTED to (b,s,t),
// pre-swizzled with keys from the permuted row index.
// ---------------------------------------------------------------------------
__global__ __launch_bounds__(256) void prep_x(const float* __restrict__ x,
                                              u16* __restrict__ xb) {
    const size_t total = (size_t)M_ * 64;   // 16B granules
    for (size_t id = (size_t)blockIdx.x * 256 + threadIdx.x; id < total;
         id += (size_t)gridDim.x * 256) {
        long r_in = (long)(id >> 6);
        int  gi   = (int)(id & 63);
        int chunk = gi >> 2;
        int g     = gi & 3;
        long rid  = permute_row(r_in);
        int cb  = (int)(rid >> 3) & 1;
        int key = (int)(rid >> 1) & 3;
        const float* src = x + r_in * 512 + chunk * 32 + g * 8;
        f32x4 v0 = *(const f32x4*)(src);
        f32x4 v1 = *(const f32x4*)(src + 4);
        u16x8 w;
        #pragma unroll
        for (int j = 0; j < 4; ++j) { w[j] = f2bf(v0[j]); w[4 + j] = f2bf(v1[j]); }
        *(u16x8*)&xb[(size_t)rid * 512 + (chunk ^ cb) * 32 + ((g ^ key) << 3)] = w;
    }
}

#define LDF(off) __builtin_bit_cast(bf16x8, *(const u16x8*)&lds[(off)])
#define MFMA16(d, a, b) d = __builtin_amdgcn_mfma_f32_16x16x32_bf16(a, b, d, 0, 0, 0)

// Epilogue LDS layout (u16 offsets; all regions dead K-loop buffers):
//   panelQK [128][QKSTR=136] @0      (cols 0..63 Q, 64..127 K; O reuses 0..63)
//   VT [2][64][72] @17408            (V transposed: [d][u], stride 72)
//   P  [2][64][72] @26624            (banded e-values, bf16, stride 72)
//   scr f32 [128][13] @35840         (S band values; ends 39168 <= 40960)
#define QKSTR 136
#define VTOFF 17408
#define POFF  26624

// ---------------------------------------------------------------------------
// FUSED qkv-GEMM + banded attention, 128-row tiles, 2 blocks/CU.
// K-loop unchanged (validated). Epilogue v4 — BOTH attention GEMMs on MFMA:
//   1) acc -> panelQK (Q,K) + VT (V transposed) + zero P; sync
//   2) S = QK^T via MFMA (10 near-diag 16x16 tiles/slab); band-scatter to scr
//   3) softmax per-thread; q==0 waves write P = e (unnormalized, bf16); sync
//   4) O_unnorm = P*V via MFMA (wave = slab,strip: 8 MFMA); O -> panel Q-region
//   5) final: o = O*inv, pre-swizzled coalesced global store (validated)
// ---------------------------------------------------------------------------
__global__ __launch_bounds__(512, 4) void gemm_attn(const u16* __restrict__ Ap,
                                                    const u16* __restrict__ Bp,
                                                    u16* __restrict__ attn) {
    __shared__ u16 lds[40960];   // A0@0 A1@8192 B0@16384 B1@28672 (u16 units)

    const int tid  = threadIdx.x;
    const int lane = tid & 63;
    const int wid  = tid >> 6;    // 0..7
    const int wm   = wid >> 2;    // 0..1
    const int wn   = wid & 3;     // 0..3
    const int fr   = lane & 15;
    const int g0   = lane >> 4;

    const int rowtile = ((blockIdx.x >> 6) << 3) | (blockIdx.x & 7);  // 0..1023
    const int h       = (blockIdx.x >> 3) & 7;
    const long row0   = (long)rowtile * 128;

    // frag LDS offsets (u16, rel. to buffer base), kk=0; kk=1 = ^32
    int aoffs[4], boffs[3];
    #pragma unroll
    for (int mf = 0; mf < 4; ++mf) {
        int lr = wm * 64 + mf * 16 + fr;          // 0..127
        aoffs[mf] = lr * 64 + (((lr >> 3) & 1) << 5) + (((g0 ^ (lr >> 1)) & 3) << 3);
    }
    #pragma unroll
    for (int nf = 0; nf < 3; ++nf) {
        int lc = wn * 48 + nf * 16 + fr;          // 0..191
        boffs[nf] = lc * 64 + (((lc >> 3) & 1) << 5) + (((g0 ^ (lc >> 1)) & 3) << 3);
    }

    const int srow = lane >> 3;        // 0..7
    const int scol = (lane & 7) * 8;   // u16 offset within 128B row window

    auto stageA = [&](int tt, int half) {       // 64 rows per half, 1 issue
        const int ab = (tt & 1) * 8192;
        int r = half * 64 + wid * 8 + srow;     // 0..127
        const u16* g = Ap + (row0 + r) * 512 + tt * 64 + scol;
        gload16(g, (void*)&lds[ab + r * 64]);
    };
    auto stageB = [&](int tt) {                 // 192 rows, 3 issues
        const int bb = 16384 + (tt & 1) * 12288;
        #pragma unroll
        for (int i = 0; i < 3; ++i) {
            int r = i * 64 + wid * 8 + srow;    // 0..191
            const u16* g = Bp + (size_t)(h * 192 + r) * 512 + tt * 64 + scol;
            gload16(g, (void*)&lds[bb + r * 64]);
        }
    };

    f32x4 acc[4][3] = {};

    // ---- prologue: [A0x2, B0x3, B1x3]; vmcnt(3) -> A0,B0 landed, B1 in flight
    stageA(0, 0); stageA(0, 1); stageB(0); stageB(1);
    asm volatile("s_waitcnt vmcnt(3)" ::: "memory");
    __builtin_amdgcn_sched_barrier(0);
    __builtin_amdgcn_s_barrier();

    #pragma unroll
    for (int t = 0; t < 8; ++t) {
        const int ab = (t & 1) * 8192;
        const int bb = 16384 + (t & 1) * 12288;
        bf16x8 af[4], bfv[3];
        // ================= phase 0: kk0 =================
        #pragma unroll
        for (int mf = 0; mf < 4; ++mf) af[mf] = LDF(ab + aoffs[mf]);
        #pragma unroll
        for (int nf = 0; nf < 3; ++nf) bfv[nf] = LDF(bb + boffs[nf]);
        if (t <= 6) { stageA(t + 1, 0); stageA(t + 1, 1); }
        __builtin_amdgcn_s_barrier();
        asm volatile("s_waitcnt lgkmcnt(0)" ::: "memory");
        __builtin_amdgcn_sched_barrier(0);
        __builtin_amdgcn_s_setprio(1);
        #pragma unroll
        for (int mf = 0; mf < 4; ++mf) {
            MFMA16(acc[mf][0], af[mf], bfv[0]);
            MFMA16(acc[mf][1], af[mf], bfv[1]);
            MFMA16(acc[mf][2], af[mf], bfv[2]);
        }
        __builtin_amdgcn_s_setprio(0);
        __builtin_amdgcn_s_barrier();
        // ================= phase 1: kk1 =================
        #pragma unroll
        for (int mf = 0; mf < 4; ++mf) af[mf] = LDF(ab + (aoffs[mf] ^ 32));
        #pragma unroll
        for (int nf = 0; nf < 3; ++nf) bfv[nf] = LDF(bb + (boffs[nf] ^ 32));
        __builtin_amdgcn_s_barrier();
        asm volatile("s_waitcnt lgkmcnt(0)" ::: "memory");
        __builtin_amdgcn_sched_barrier(0);
        __builtin_amdgcn_s_setprio(1);
        #pragma unroll
        for (int mf = 0; mf < 4; ++mf) {
            MFMA16(acc[mf][0], af[mf], bfv[0]);
            MFMA16(acc[mf][1], af[mf], bfv[1]);
            MFMA16(acc[mf][2], af[mf], bfv[2]);
        }
        __builtin_amdgcn_s_setprio(0);
        __builtin_amdgcn_s_barrier();
        // ================= phase 2: B prefetch (all B(t) reads retired) =====
        if (t <= 6) {
            if (t <= 5) {
                stageB(t + 2);
                asm volatile("s_waitcnt vmcnt(3)" ::: "memory");
            } else {
                asm volatile("s_waitcnt vmcnt(0)" ::: "memory");   // A7,B7 landed
            }
            __builtin_amdgcn_sched_barrier(0);
            __builtin_amdgcn_s_barrier();
        }
    }

    // ---- epilogue 1: acc -> panelQK (Q,K) + VT (V transposed); zero P ----
    __builtin_amdgcn_sched_barrier(0);
    #pragma unroll
    for (int mf = 0; mf < 4; ++mf) {
        #pragma unroll
        for (int nf = 0; nf < 3; ++nf) {
            #pragma unroll
            for (int r = 0; r < 4; ++r) {
                int row = wm * 64 + mf * 16 + (lane >> 4) * 4 + r;
                int col = wn * 48 + nf * 16 + fr;
                u16 v = f2bf(acc[mf][nf][r]);
                if (col < 128) {
                    lds[row * QKSTR + col] = v;
                } else {
                    lds[VTOFF + (row >> 6) * 4608 + (col - 128) * 72 + (row & 63)] = v;
                }
            }
        }
    }
    {   // zero P: 9216 u16 = 512*16 + 128*8
        u16x8 z = {0, 0, 0, 0, 0, 0, 0, 0};
        *(u16x8*)&lds[POFF + tid * 16]     = z;
        *(u16x8*)&lds[POFF + tid * 16 + 8] = z;
        if (tid < 128) *(u16x8*)&lds[POFF + 8192 + tid * 8] = z;
    }
    __syncthreads();

    float* scr = (float*)&lds[35840];   // [128 rows][13] f32

    // ---- epilogue 2: S = QK^T via MFMA; masked band scatter to scr ----
    {
        const int sl = wid >> 2;        // slab
        const int I  = wid & 3;         // row strip (16 rows)
        const int abase = (sl * 64 + I * 16 + fr) * QKSTR;
        bf16x8 qa0 = LDF(abase + g0 * 8);
        bf16x8 qa1 = LDF(abase + 32 + g0 * 8);
        #pragma unroll
        for (int dj = -1; dj <= 1; ++dj) {
            int J = I + dj;
            if (J >= 0 && J <= 3) {     // wave-uniform branch
                const int bbase = (sl * 64 + J * 16 + fr) * QKSTR + 64;
                bf16x8 kb0 = LDF(bbase + g0 * 8);
                bf16x8 kb1 = LDF(bbase + 32 + g0 * 8);
                f32x4 sv = {0.f, 0.f, 0.f, 0.f};
                MFMA16(sv, qa0, kb0);
                MFMA16(sv, qa1, kb1);
                #pragma unroll
                for (int r = 0; r < 4; ++r) {
                    int row = I * 16 + (lane >> 4) * 4 + r;   // 0..63 in slab
                    int u   = J * 16 + fr;
                    int i   = u - row + WIN_;
                    if (i >= 0 && i < 11)
                        scr[(sl * 64 + row) * 13 + i] = sv[r];
                }
            }
        }
    }
    __syncthreads();

    // ---- epilogue 3: softmax; q==0 waves write P = e (bf16, unnormalized) --
    const int slab = wid >> 2;
    const int q    = wid & 3;
    const int t    = lane;
    const int prow = slab * 64 + t;
    float inv;
    {
        float p[11];
        float m = -1e30f;
        #pragma unroll
        for (int i = 0; i < 11; ++i) {
            int u = t - WIN_ + i;
            if (u >= 0 && u < 64) {
                p[i] = scr[prow * 13 + i] * 0.125f;
                m = fmaxf(m, p[i]);
            } else {
                p[i] = -1e30f;
            }
        }
        float sum = 0.f;
        #pragma unroll
        for (int i = 0; i < 11; ++i) {
            int u = t - WIN_ + i;
            float e = (u >= 0 && u < 64) ? __expf(p[i] - m) : 0.f;
            p[i] = e;
            sum += e;
        }
        inv = 1.f / sum;
        if (q == 0) {
            #pragma unroll
            for (int i = 0; i < 11; ++i) {
                int u = t - WIN_ + i;
                if (u >= 0 && u < 64)
                    lds[POFF + slab * 4608 + t * 72 + u] = f2bf(p[i]);
            }
        }
    }
    __syncthreads();

    // ---- epilogue 4: O_unnorm = P*V via MFMA; O -> panel cols 0..63 ----
    {
        const int I = q;                // row strip
        const int pb = POFF + slab * 4608 + (I * 16 + fr) * 72;
        bf16x8 pa0 = LDF(pb + g0 * 8);
        bf16x8 pa1 = LDF(pb + 32 + g0 * 8);
        #pragma unroll
        for (int dt = 0; dt < 4; ++dt) {
            const int vb = VTOFF + slab * 4608 + (dt * 16 + fr) * 72;
            bf16x8 vb0 = LDF(vb + g0 * 8);
            bf16x8 vb1 = LDF(vb + 32 + g0 * 8);
            f32x4 ov = {0.f, 0.f, 0.f, 0.f};
            MFMA16(ov, pa0, vb0);
            MFMA16(ov, pa1, vb1);
            #pragma unroll
            for (int r = 0; r < 4; ++r) {
                int row = I * 16 + (lane >> 4) * 4 + r;
                lds[(slab * 64 + row) * QKSTR + dt * 16 + fr] = f2bf(ov[r]);
            }
        }
    }
    __syncthreads();

    // ---- epilogue 5: scale by inv; pre-swizzled coalesced global store ----
    {
        float o[16];
        #pragma unroll
        for (int cc = 0; cc < 2; ++cc) {
            u16x8 v = *(const u16x8*)&lds[prow * QKSTR + q * 16 + cc * 8];
            #pragma unroll
            for (int j = 0; j < 8; ++j) o[cc * 8 + j] = bf2f(v[j]) * inv;
        }
        long rid = row0 + prow;
        int s = (int)(rid >> 6) & 1023;
        size_t rowbase = (size_t)rid * C_;
        const int cb  = (s >> 3) & 1;
        const int key = (s >> 1) & 3;
        #pragma unroll
        for (int cc = 0; cc < 2; ++cc) {
            int c = q * 2 + cc;
            u16x8 w;
            #pragma unroll
            for (int j = 0; j < 8; ++j) w[j] = f2bf(o[cc * 8 + j]);
            int off = (((2 * h + (c >> 2)) ^ cb) << 5) + (((c & 3) ^ key) << 3);
            *(u16x8*)&attn[rowbase + off] = w;
        }
    }
}

// ---------------------------------------------------------------------------
// 256x256 8-phase pipelined GEMM (r11-validated) — used for out = attn@W_out.
// ---------------------------------------------------------------------------
template<int NCOL, bool OUT_BF16, bool A_PERM>
__global__ __launch_bounds__(512, 2) void gemm8_k(const u16* __restrict__ Ap,
                                                  const u16* __restrict__ Bp,
                                                  void* __restrict__ Dp, int gx) {
    __shared__ u16 lds[65536];   // dbuf0{A,B} | dbuf1{A,B}, 16384 u16 each

    const int tid  = threadIdx.x;
    const int lane = tid & 63;
    const int wid  = tid >> 6;
    const int wm   = wid >> 2;
    const int wn   = wid & 3;
    const int fr   = lane & 15;
    const int g0   = lane >> 4;

    const int nwg = gridDim.x;
    const int q8  = nwg >> 3;
    const int bid = blockIdx.x;
    const int wg  = (bid & 7) * q8 + (bid >> 3);
    const int bx  = wg % gx;
    const int by  = wg / gx;
    const long row0 = (long)by * 256;
    const int  col0 = bx * 256;

    int aoffs[8], boffs[4];
    #pragma unroll
    for (int mf = 0; mf < 8; ++mf) {
        int lr = wm * 128 + mf * 16 + fr;
        aoffs[mf] = lr * 64 + (((lr >> 3) & 1) << 5) + (((g0 ^ (lr >> 1)) & 3) << 3);
    }
    #pragma unroll
    for (int nf = 0; nf < 4; ++nf) {
        int lc = wn * 64 + nf * 16 + fr;
        boffs[nf] = lc * 64 + (((lc >> 3) & 1) << 5) + (((g0 ^ (lc >> 1)) & 3) << 3);
    }

    const int srow = lane >> 3;
    const int scol = (lane & 7) * 8;

    long arow_phys[4];
    #pragma unroll
    for (int half = 0; half < 2; ++half)
        #pragma unroll
        for (int i = 0; i < 2; ++i) {
            int r = half * 128 + i * 64 + wid * 8 + srow;
            long grow = row0 + r;
            arow_phys[half * 2 + i] = A_PERM ? permute_row(grow) : grow;
        }

    auto stageA = [&](int tt, int half) {
        const int ab = (tt & 1) * 32768;
        #pragma unroll
        for (int i = 0; i < 2; ++i) {
            int r = half * 128 + i * 64 + wid * 8 + srow;
            const u16* g = Ap + arow_phys[half * 2 + i] * 512 + tt * 64 + scol;
            gload16(g, (void*)&lds[ab + r * 64]);
        }
    };
    auto stageB = [&](int tt, int half) {
        const int ab = (tt & 1) * 32768;
        #pragma unroll
        for (int i = 0; i < 2; ++i) {
            int r = half * 128 + i * 64 + wid * 8 + srow;
            const u16* g = Bp + (size_t)(col0 + r) * 512 + tt * 64 + scol;
            gload16(g, (void*)&lds[ab + 16384 + r * 64]);
        }
    };

    f32x4 acc[8][4] = {};

    stageA(0, 0); stageA(0, 1); stageB(0, 0); stageB(0, 1);
    stageB(1, 0); stageB(1, 1);
    asm volatile("s_waitcnt vmcnt(4)" ::: "memory");
    __builtin_amdgcn_sched_barrier(0);
    __builtin_amdgcn_s_barrier();

    #pragma unroll
    for (int t = 0; t < 8; ++t) {
        const int ab = (t & 1) * 32768;
        bf16x8 af0[8], af1[8], bf0[4], bf1[4];
        // phase 0
        #pragma unroll
        for (int mf = 0; mf < 4; ++mf) af0[mf] = LDF(ab + aoffs[mf]);
        #pragma unroll
        for (int nf = 0; nf < 4; ++nf) bf0[nf] = LDF(ab + 16384 + boffs[nf]);
        if (t <= 6) stageA(t + 1, 0);
        __builtin_amdgcn_s_barrier();
        asm volatile("s_waitcnt lgkmcnt(0)" ::: "memory");
        __builtin_amdgcn_sched_barrier(0);
        __builtin_amdgcn_s_setprio(1);
        #pragma unroll
        for (int mf = 0; mf < 4; ++mf) {
            MFMA16(acc[mf][0], af0[mf], bf0[0]);
            MFMA16(acc[mf][1], af0[mf], bf0[1]);
            MFMA16(acc[mf][2], af0[mf], bf0[2]);
            MFMA16(acc[mf][3], af0[mf], bf0[3]);
        }
        __builtin_amdgcn_s_setprio(0);
        __builtin_amdgcn_s_barrier();
        // phase 1
        #pragma unroll
        for (int mf = 4; mf < 8; ++mf) af0[mf] = LDF(ab + aoffs[mf]);
        #pragma unroll
        for (int nf = 0; nf < 4; ++nf) bf1[nf] = LDF(ab + 16384 + (boffs[nf] ^ 32));
        if (t <= 6) stageA(t + 1, 1);
        __builtin_amdgcn_s_barrier();
        asm volatile("s_waitcnt lgkmcnt(0)" ::: "memory");
        __builtin_amdgcn_sched_barrier(0);
        __builtin_amdgcn_s_setprio(1);
        #pragma unroll
        for (int mf = 4; mf < 8; ++mf) {
            MFMA16(acc[mf][0], af0[mf], bf0[0]);
            MFMA16(acc[mf][1], af0[mf], bf0[1]);
            MFMA16(acc[mf][2], af0[mf], bf0[2]);
            MFMA16(acc[mf][3], af0[mf], bf0[3]);
        }
        __builtin_amdgcn_s_setprio(0);
        __builtin_amdgcn_s_barrier();
        // phase 2
        #pragma unroll
        for (int mf = 0; mf < 4; ++mf) af1[mf] = LDF(ab + (aoffs[mf] ^ 32));
        if (t <= 5) stageB(t + 2, 0);
        __builtin_amdgcn_s_barrier();
        asm volatile("s_waitcnt lgkmcnt(0)" ::: "memory");
        __builtin_amdgcn_sched_barrier(0);
        __builtin_amdgcn_s_setprio(1);
        #pragma unroll
        for (int mf = 0; mf < 4; ++mf) {
            MFMA16(acc[mf][0], af1[mf], bf1[0]);
            MFMA16(acc[mf][1], af1[mf], bf1[1]);
            MFMA16(acc[mf][2], af1[mf], bf1[2]);
            MFMA16(acc[mf][3], af1[mf], bf1[3]);
        }
        __builtin_amdgcn_s_setprio(0);
        __builtin_amdgcn_s_barrier();
        // phase 3
        #pragma unroll
        for (int mf = 4; mf < 8; ++mf) af1[mf] = LDF(ab + (aoffs[mf] ^ 32));
        if (t <= 5) stageB(t + 2, 1);
        __builtin_amdgcn_s_barrier();
        asm volatile("s_waitcnt lgkmcnt(0)" ::: "memory");
        __builtin_amdgcn_sched_barrier(0);
        __builtin_amdgcn_s_setprio(1);
        #pragma unroll
        for (int mf = 4; mf < 8; ++mf) {
            MFMA16(acc[mf][0], af1[mf], bf1[0]);
            MFMA16(acc[mf][1], af1[mf], bf1[1]);
            MFMA16(acc[mf][2], af1[mf], bf1[2]);
            MFMA16(acc[mf][3], af1[mf], bf1[3]);
        }
        __builtin_amdgcn_s_setprio(0);
        if (t <= 5) {
            asm volatile("s_waitcnt vmcnt(4)" ::: "memory");
        } else if (t == 6) {
            asm volatile("s_waitcnt vmcnt(0)" ::: "memory");
        }
        __builtin_amdgcn_sched_barrier(0);
        __builtin_amdgcn_s_barrier();
    }

    #pragma unroll
    for (int mf = 0; mf < 8; ++mf) {
        #pragma unroll
        for (int nf = 0; nf < 4; ++nf) {
            #pragma unroll
            for (int r = 0; r < 4; ++r) {
                long grow = row0 + wm * 128 + mf * 16 + (lane >> 4) * 4 + r;
                int  gcol = col0 + wn * 64 + nf * 16 + fr;
                float v = acc[mf][nf][r];
                if constexpr (OUT_BF16) ((u16*)Dp)[grow * NCOL + gcol] = f2bf(v);
                else                    ((float*)Dp)[grow * NCOL + gcol] = v;
            }
        }
    }
}

// ---------------------------------------------------------------------------
extern "C" void kernel_launch(void* const* d_in, const int* in_sizes, int n_in,
                              void* d_out, int out_size, void* d_ws, size_t ws_size,
                              hipStream_t stream) {
    const float* x    = (const float*)d_in[0];   // (B, N, C) fp32
    const float* Wqkv = (const float*)d_in[1];   // (512, 1536) fp32
    const float* Wout = (const float*)d_in[2];   // (512, 512) fp32
    float* out = (float*)d_out;

    const size_t xc_elems = (size_t)M_ * C_;     // 67.1M u16
    // layout: xb | attn_buf | WqkvT2 | WoutT  (~272 MB total, no aliasing)
    u16* xb       = (u16*)d_ws;
    u16* attn_buf = xb + xc_elems;
    u16* WqkvT2   = attn_buf + xc_elems;
    u16* WoutT    = WqkvT2 + (size_t)1536 * 512;
    if (ws_size < ((size_t)(WoutT + (size_t)512 * 512) - (size_t)d_ws)) return;

    // 1) weight + activation prep
    prep_w2<<<(1536 * 64) / 256, 256, 0, stream>>>(Wqkv, WqkvT2);
    prep_w<<<(512 * 64) / 256, 256, 0, stream>>>(Wout, WoutT, 512);
    prep_x<<<8192, 256, 0, stream>>>(x, xb);

    // 2) fused qkv-GEMM + banded attention (128-row tiles, 2 blocks/CU,
    //    full-MFMA attention epilogue)
    gemm_attn<<<8192, 512, 0, stream>>>(xb, WqkvT2, attn_buf);

    // 3) out = attn @ W_out
    gemm8_k<512, false, true><<<1024, 512, 0, stream>>>(attn_buf, WoutT, (void*)out, 2);
}

// Round 23
// 454.099 us; speedup vs baseline: 1.0515x; 1.0515x over previous
//
#include <hip/hip_runtime.h>
#include <stdint.h>

// Problem constants (fixed instance from setup_inputs)
#define B_   2
#define T_   64
#define S_   1024
#define C_   512
#define H_   8
#define N_   (T_ * S_)      // 65536
#define M_   (B_ * N_)      // 131072
#define WIN_ 5

typedef unsigned short u16;
typedef __bf16 bf16;
typedef __bf16 bf16x8 __attribute__((ext_vector_type(8)));
typedef float  f32x4  __attribute__((ext_vector_type(4)));
typedef u16    u16x8  __attribute__((ext_vector_type(8)));

static __device__ __forceinline__ u16 f2bf(float f) {
    return __builtin_bit_cast(u16, (bf16)f);   // RNE
}
static __device__ __forceinline__ float bf2f(u16 u) {
    return __builtin_bit_cast(float, (uint32_t)u << 16);
}
// async global->LDS, 16B per lane; LDS dest is wave-uniform base + lane*16
static __device__ __forceinline__ void gload16(const void* g, void* l) {
    __builtin_amdgcn_global_load_lds(
        (const __attribute__((address_space(1))) void*)g,
        (__attribute__((address_space(3))) void*)l, 16, 0, 0);
}
// row permutation: logical (b,t,s) flat row -> physical (b,s,t) flat row
static __device__ __forceinline__ long permute_row(long grow) {
    int b = (int)(grow >> 16);
    int t = (int)(grow >> 10) & 63;
    int s = (int)grow & 1023;
    return ((long)((b << 10) | s)) * 64 + t;
}

// Pre-swizzle layout (bf16 [row][512] operands): logical (chunk c in [0,16),
// granule g in [0,4), elem j) stored at
// r*512 + (c ^ ((rl>>3)&1))*32 + ((g ^ ((rl>>1)&3))<<3) + j,
// keys from the TILE-LOCAL row rl. 0 conflicts measured.

// ---------------------------------------------------------------------------
// Wout prep: W [512][512] fp32 -> WT [512][512] bf16, pre-swizzled.
// ---------------------------------------------------------------------------
__global__ __launch_bounds__(256) void prep_w(const float* __restrict__ W,
                                              u16* __restrict__ WT, int NCOL) {
    int id = blockIdx.x * 256 + threadIdx.x;
    int n  = id % NCOL;
    int gi = id / NCOL;
    int chunk = gi >> 2;
    int g     = gi & 3;
    int k0 = chunk * 32 + g * 8;
    int cs = chunk ^ ((n >> 3) & 1);
    int gs = g ^ ((n >> 1) & 3);
    u16x8 w;
    #pragma unroll
    for (int j = 0; j < 8; ++j) w[j] = f2bf(W[(size_t)(k0 + j) * NCOL + n]);
    *(u16x8*)&WT[(size_t)n * 512 + cs * 32 + gs * 8] = w;
}

// ---------------------------------------------------------------------------
// Wqkv prep, head-grouped: W [512][1536] fp32, col n = which*512 + h*64 + d
// -> WT2 row n' = h*192 + which*64 + d, bf16, pre-swizzled with keys from the
// PANEL-LOCAL row which*64+d.
// ---------------------------------------------------------------------------
__global__ __launch_bounds__(256) void prep_w2(const float* __restrict__ W,
                                               u16* __restrict__ WT2) {
    int id = blockIdx.x * 256 + threadIdx.x;
    int n  = id % 1536;
    int gi = id / 1536;
    int chunk = gi >> 2;
    int g     = gi & 3;
    int k0 = chunk * 32 + g * 8;
    int which = n >> 9;
    int h     = (n >> 6) & 7;
    int d     = n & 63;
    int rloc  = which * 64 + d;          // 0..191 panel-local row
    long np   = h * 192 + rloc;
    int cs = chunk ^ ((rloc >> 3) & 1);
    int gs = g ^ ((rloc >> 1) & 3);
    u16x8 w;
    #pragma unroll
    for (int j = 0; j < 8; ++j) w[j] = f2bf(W[(size_t)(k0 + j) * 1536 + n]);
    *(u16x8*)&WT2[(size_t)np * 512 + cs * 32 + gs * 8] = w;
}

// ---------------------------------------------------------------------------
// x prep: x [M][512] fp32 (rows (b,t,s)) -> xb bf16 rows PERMUTED to (b,s,t),
// pre-swizzled with keys from the permuted row index.
// ---------------------------------------------------------------------------
__global__ __launch_bounds__(256) void prep_x(const float* __restrict__ x,
                                              u16* __restrict__ xb) {
    const size_t total = (size_t)M_ * 64;   // 16B granules
    for (size_t id = (size_t)blockIdx.x * 256 + threadIdx.x; id < total;
         id += (size_t)gridDim.x * 256) {
        long r_in = (long)(id >> 6);
        int  gi   = (int)(id & 63);
        int chunk = gi >> 2;
        int g     = gi & 3;
        long rid  = permute_row(r_in);
        int cb  = (int)(rid >> 3) & 1;
        int key = (int)(rid >> 1) & 3;
        const float* src = x + r_in * 512 + chunk * 32 + g * 8;
        f32x4 v0 = *(const f32x4*)(src);
        f32x4 v1 = *(const f32x4*)(src + 4);
        u16x8 w;
        #pragma unroll
        for (int j = 0; j < 4; ++j) { w[j] = f2bf(v0[j]); w[4 + j] = f2bf(v1[j]); }
        *(u16x8*)&xb[(size_t)rid * 512 + (chunk ^ cb) * 32 + ((g ^ key) << 3)] = w;
    }
}

#define LDF(off) __builtin_bit_cast(bf16x8, *(const u16x8*)&lds[(off)])
#define MFMA16(d, a, b) d = __builtin_amdgcn_mfma_f32_16x16x32_bf16(a, b, d, 0, 0, 0)

#define PSTR 200   // panel row stride (u16): pad keeps reads bank-bijective

// ---------------------------------------------------------------------------
// FUSED qkv-GEMM + banded attention, 128-row tiles, 2 blocks/CU (r18 base).
// K-loop unchanged (validated). Epilogue v3 (r21-validated BEST): S = QK^T on
// the MATRIX PIPE (10 near-diag 16x16 tiles/slab; wave = (slab, strip I),
// J in {I-1,I,I+1}: 8 ds_read_b128 + <=6 MFMA), masked band scatter to
// scr[row][13] f32 (stride 13 coprime to 32). Softmax + per-thread PV +
// pre-swizzled stores (validated r19/r20).
// ---------------------------------------------------------------------------
__global__ __launch_bounds__(512, 4) void gemm_attn(const u16* __restrict__ Ap,
                                                    const u16* __restrict__ Bp,
                                                    u16* __restrict__ attn) {
    __shared__ u16 lds[40960];   // A0@0 A1@8192 B0@16384 B1@28672 (u16 units)

    const int tid  = threadIdx.x;
    const int lane = tid & 63;
    const int wid  = tid >> 6;    // 0..7
    const int wm   = wid >> 2;    // 0..1
    const int wn   = wid & 3;     // 0..3
    const int fr   = lane & 15;
    const int g0   = lane >> 4;

    const int rowtile = ((blockIdx.x >> 6) << 3) | (blockIdx.x & 7);  // 0..1023
    const int h       = (blockIdx.x >> 3) & 7;
    const long row0   = (long)rowtile * 128;

    // frag LDS offsets (u16, rel. to buffer base), kk=0; kk=1 = ^32
    int aoffs[4], boffs[3];
    #pragma unroll
    for (int mf = 0; mf < 4; ++mf) {
        int lr = wm * 64 + mf * 16 + fr;          // 0..127
        aoffs[mf] = lr * 64 + (((lr >> 3) & 1) << 5) + (((g0 ^ (lr >> 1)) & 3) << 3);
    }
    #pragma unroll
    for (int nf = 0; nf < 3; ++nf) {
        int lc = wn * 48 + nf * 16 + fr;          // 0..191
        boffs[nf] = lc * 64 + (((lc >> 3) & 1) << 5) + (((g0 ^ (lc >> 1)) & 3) << 3);
    }

    const int srow = lane >> 3;        // 0..7
    const int scol = (lane & 7) * 8;   // u16 offset within 128B row window

    auto stageA = [&](int tt, int half) {       // 64 rows per half, 1 issue
        const int ab = (tt & 1) * 8192;
        int r = half * 64 + wid * 8 + srow;     // 0..127
        const u16* g = Ap + (row0 + r) * 512 + tt * 64 + scol;
        gload16(g, (void*)&lds[ab + r * 64]);
    };
    auto stageB = [&](int tt) {                 // 192 rows, 3 issues
        const int bb = 16384 + (tt & 1) * 12288;
        #pragma unroll
        for (int i = 0; i < 3; ++i) {
            int r = i * 64 + wid * 8 + srow;    // 0..191
            const u16* g = Bp + (size_t)(h * 192 + r) * 512 + tt * 64 + scol;
            gload16(g, (void*)&lds[bb + r * 64]);
        }
    };

    f32x4 acc[4][3] = {};

    // ---- prologue: [A0x2, B0x3, B1x3]; vmcnt(3) -> A0,B0 landed, B1 in flight
    stageA(0, 0); stageA(0, 1); stageB(0); stageB(1);
    asm volatile("s_waitcnt vmcnt(3)" ::: "memory");
    __builtin_amdgcn_sched_barrier(0);
    __builtin_amdgcn_s_barrier();

    #pragma unroll
    for (int t = 0; t < 8; ++t) {
        const int ab = (t & 1) * 8192;
        const int bb = 16384 + (t & 1) * 12288;
        bf16x8 af[4], bfv[3];
        // ================= phase 0: kk0 =================
        #pragma unroll
        for (int mf = 0; mf < 4; ++mf) af[mf] = LDF(ab + aoffs[mf]);
        #pragma unroll
        for (int nf = 0; nf < 3; ++nf) bfv[nf] = LDF(bb + boffs[nf]);
        if (t <= 6) { stageA(t + 1, 0); stageA(t + 1, 1); }
        __builtin_amdgcn_s_barrier();
        asm volatile("s_waitcnt lgkmcnt(0)" ::: "memory");
        __builtin_amdgcn_sched_barrier(0);
        __builtin_amdgcn_s_setprio(1);
        #pragma unroll
        for (int mf = 0; mf < 4; ++mf) {
            MFMA16(acc[mf][0], af[mf], bfv[0]);
            MFMA16(acc[mf][1], af[mf], bfv[1]);
            MFMA16(acc[mf][2], af[mf], bfv[2]);
        }
        __builtin_amdgcn_s_setprio(0);
        __builtin_amdgcn_s_barrier();
        // ================= phase 1: kk1 =================
        #pragma unroll
        for (int mf = 0; mf < 4; ++mf) af[mf] = LDF(ab + (aoffs[mf] ^ 32));
        #pragma unroll
        for (int nf = 0; nf < 3; ++nf) bfv[nf] = LDF(bb + (boffs[nf] ^ 32));
        __builtin_amdgcn_s_barrier();
        asm volatile("s_waitcnt lgkmcnt(0)" ::: "memory");
        __builtin_amdgcn_sched_barrier(0);
        __builtin_amdgcn_s_setprio(1);
        #pragma unroll
        for (int mf = 0; mf < 4; ++mf) {
            MFMA16(acc[mf][0], af[mf], bfv[0]);
            MFMA16(acc[mf][1], af[mf], bfv[1]);
            MFMA16(acc[mf][2], af[mf], bfv[2]);
        }
        __builtin_amdgcn_s_setprio(0);
        __builtin_amdgcn_s_barrier();
        // ================= phase 2: B prefetch (all B(t) reads retired) =====
        if (t <= 6) {
            if (t <= 5) {
                stageB(t + 2);
                asm volatile("s_waitcnt vmcnt(3)" ::: "memory");
            } else {
                asm volatile("s_waitcnt vmcnt(0)" ::: "memory");   // A7,B7 landed
            }
            __builtin_amdgcn_sched_barrier(0);
            __builtin_amdgcn_s_barrier();
        }
    }

    // ---- epilogue: acc -> LDS panel [128][PSTR] bf16, linear cols ----
    __builtin_amdgcn_sched_barrier(0);
    #pragma unroll
    for (int mf = 0; mf < 4; ++mf) {
        #pragma unroll
        for (int nf = 0; nf < 3; ++nf) {
            #pragma unroll
            for (int r = 0; r < 4; ++r) {
                int row = wm * 64 + mf * 16 + (lane >> 4) * 4 + r;
                int col = wn * 48 + nf * 16 + fr;
                lds[row * PSTR + col] = f2bf(acc[mf][nf][r]);
            }
        }
    }
    __syncthreads();

    float* scr = (float*)&lds[25600];   // [128 rows][13] f32 (stride 13)

    // ---- S = QK^T via MFMA (wave = slab, row-strip I); masked band scatter
    {
        const int slab = wid >> 2;      // 0..1
        const int I    = wid & 3;       // row strip (16 rows)
        const int abase = (slab * 64 + I * 16 + fr) * PSTR;
        bf16x8 qa0 = LDF(abase + g0 * 8);
        bf16x8 qa1 = LDF(abase + 32 + g0 * 8);
        #pragma unroll
        for (int dj = -1; dj <= 1; ++dj) {
            int J = I + dj;
            if (J >= 0 && J <= 3) {     // wave-uniform branch
                const int bbase = (slab * 64 + J * 16 + fr) * PSTR + 64;
                bf16x8 kb0 = LDF(bbase + g0 * 8);
                bf16x8 kb1 = LDF(bbase + 32 + g0 * 8);
                f32x4 sv = {0.f, 0.f, 0.f, 0.f};
                MFMA16(sv, qa0, kb0);
                MFMA16(sv, qa1, kb1);
                #pragma unroll
                for (int r = 0; r < 4; ++r) {
                    int row = I * 16 + (lane >> 4) * 4 + r;   // 0..63 in slab
                    int u   = J * 16 + fr;
                    int i   = u - row + WIN_;
                    if (i >= 0 && i < 11)
                        scr[(slab * 64 + row) * 13 + i] = sv[r];
                }
            }
        }
    }
    __syncthreads();

    // ---- softmax + PV: wave = (slab = wid>>2, d-quarter q = wid&3) ----
    {
        const int slab = wid >> 2;
        const int q    = wid & 3;
        const int t    = lane;
        const int prow = slab * 64 + t;

        float p[11];
        float m = -1e30f;
        #pragma unroll
        for (int i = 0; i < 11; ++i) {
            int u = t - WIN_ + i;
            if (u >= 0 && u < 64) {
                p[i] = scr[prow * 13 + i] * 0.125f;
                m = fmaxf(m, p[i]);
            } else {
                p[i] = -1e30f;
            }
        }
        float sum = 0.f;
        #pragma unroll
        for (int i = 0; i < 11; ++i) {
            int u = t - WIN_ + i;
            float e = (u >= 0 && u < 64) ? __expf(p[i] - m) : 0.f;
            p[i] = e;
            sum += e;
        }
        const float inv = 1.f / sum;

        // PV for this quarter's 16 output channels
        float o[16];
        #pragma unroll
        for (int d = 0; d < 16; ++d) o[d] = 0.f;
        #pragma unroll
        for (int i = 0; i < 11; ++i) {
            int u = t - WIN_ + i;
            if (u >= 0 && u < 64) {
                const int ub = (slab * 64 + u) * PSTR + 128;
                float pv = p[i] * inv;
                #pragma unroll
                for (int cc = 0; cc < 2; ++cc) {
                    u16x8 vv = *(const u16x8*)&lds[ub + (q * 2 + cc) * 8];
                    #pragma unroll
                    for (int j = 0; j < 8; ++j) o[cc * 8 + j] += pv * bf2f(vv[j]);
                }
            }
        }
        // pre-swizzled store (2 chunks c = 2q, 2q+1); keys from s (gemm3 A)
        long rid = row0 + prow;
        int s = (int)(rid >> 6) & 1023;
        size_t rowbase = (size_t)rid * C_;
        const int cb  = (s >> 3) & 1;
        const int key = (s >> 1) & 3;
        #pragma unroll
        for (int cc = 0; cc < 2; ++cc) {
            int c = q * 2 + cc;
            u16x8 w;
            #pragma unroll
            for (int j = 0; j < 8; ++j) w[j] = f2bf(o[cc * 8 + j]);
            int off = (((2 * h + (c >> 2)) ^ cb) << 5) + (((c & 3) ^ key) << 3);
            *(u16x8*)&attn[rowbase + off] = w;
        }
    }
}

// ---------------------------------------------------------------------------
// 256x256 8-phase pipelined GEMM (r11-validated) — used for out = attn@W_out.
// ---------------------------------------------------------------------------
template<int NCOL, bool OUT_BF16, bool A_PERM>
__global__ __launch_bounds__(512, 2) void gemm8_k(const u16* __restrict__ Ap,
                                                  const u16* __restrict__ Bp,
                                                  void* __restrict__ Dp, int gx) {
    __shared__ u16 lds[65536];   // dbuf0{A,B} | dbuf1{A,B}, 16384 u16 each

    const int tid  = threadIdx.x;
    const int lane = tid & 63;
    const int wid  = tid >> 6;
    const int wm   = wid >> 2;
    const int wn   = wid & 3;
    const int fr   = lane & 15;
    const int g0   = lane >> 4;

    const int nwg = gridDim.x;
    const int q8  = nwg >> 3;
    const int bid = blockIdx.x;
    const int wg  = (bid & 7) * q8 + (bid >> 3);
    const int bx  = wg % gx;
    const int by  = wg / gx;
    const long row0 = (long)by * 256;
    const int  col0 = bx * 256;

    int aoffs[8], boffs[4];
    #pragma unroll
    for (int mf = 0; mf < 8; ++mf) {
        int lr = wm * 128 + mf * 16 + fr;
        aoffs[mf] = lr * 64 + (((lr >> 3) & 1) << 5) + (((g0 ^ (lr >> 1)) & 3) << 3);
    }
    #pragma unroll
    for (int nf = 0; nf < 4; ++nf) {
        int lc = wn * 64 + nf * 16 + fr;
        boffs[nf] = lc * 64 + (((lc >> 3) & 1) << 5) + (((g0 ^ (lc >> 1)) & 3) << 3);
    }

    const int srow = lane >> 3;
    const int scol = (lane & 7) * 8;

    long arow_phys[4];
    #pragma unroll
    for (int half = 0; half < 2; ++half)
        #pragma unroll
        for (int i = 0; i < 2; ++i) {
            int r = half * 128 + i * 64 + wid * 8 + srow;
            long grow = row0 + r;
            arow_phys[half * 2 + i] = A_PERM ? permute_row(grow) : grow;
        }

    auto stageA = [&](int tt, int half) {
        const int ab = (tt & 1) * 32768;
        #pragma unroll
        for (int i = 0; i < 2; ++i) {
            int r = half * 128 + i * 64 + wid * 8 + srow;
            const u16* g = Ap + arow_phys[half * 2 + i] * 512 + tt * 64 + scol;
            gload16(g, (void*)&lds[ab + r * 64]);
        }
    };
    auto stageB = [&](int tt, int half) {
        const int ab = (tt & 1) * 32768;
        #pragma unroll
        for (int i = 0; i < 2; ++i) {
            int r = half * 128 + i * 64 + wid * 8 + srow;
            const u16* g = Bp + (size_t)(col0 + r) * 512 + tt * 64 + scol;
            gload16(g, (void*)&lds[ab + 16384 + r * 64]);
        }
    };

    f32x4 acc[8][4] = {};

    stageA(0, 0); stageA(0, 1); stageB(0, 0); stageB(0, 1);
    stageB(1, 0); stageB(1, 1);
    asm volatile("s_waitcnt vmcnt(4)" ::: "memory");
    __builtin_amdgcn_sched_barrier(0);
    __builtin_amdgcn_s_barrier();

    #pragma unroll
    for (int t = 0; t < 8; ++t) {
        const int ab = (t & 1) * 32768;
        bf16x8 af0[8], af1[8], bf0[4], bf1[4];
        // phase 0
        #pragma unroll
        for (int mf = 0; mf < 4; ++mf) af0[mf] = LDF(ab + aoffs[mf]);
        #pragma unroll
        for (int nf = 0; nf < 4; ++nf) bf0[nf] = LDF(ab + 16384 + boffs[nf]);
        if (t <= 6) stageA(t + 1, 0);
        __builtin_amdgcn_s_barrier();
        asm volatile("s_waitcnt lgkmcnt(0)" ::: "memory");
        __builtin_amdgcn_sched_barrier(0);
        __builtin_amdgcn_s_setprio(1);
        #pragma unroll
        for (int mf = 0; mf < 4; ++mf) {
            MFMA16(acc[mf][0], af0[mf], bf0[0]);
            MFMA16(acc[mf][1], af0[mf], bf0[1]);
            MFMA16(acc[mf][2], af0[mf], bf0[2]);
            MFMA16(acc[mf][3], af0[mf], bf0[3]);
        }
        __builtin_amdgcn_s_setprio(0);
        __builtin_amdgcn_s_barrier();
        // phase 1
        #pragma unroll
        for (int mf = 4; mf < 8; ++mf) af0[mf] = LDF(ab + aoffs[mf]);
        #pragma unroll
        for (int nf = 0; nf < 4; ++nf) bf1[nf] = LDF(ab + 16384 + (boffs[nf] ^ 32));
        if (t <= 6) stageA(t + 1, 1);
        __builtin_amdgcn_s_barrier();
        asm volatile("s_waitcnt lgkmcnt(0)" ::: "memory");
        __builtin_amdgcn_sched_barrier(0);
        __builtin_amdgcn_s_setprio(1);
        #pragma unroll
        for (int mf = 4; mf < 8; ++mf) {
            MFMA16(acc[mf][0], af0[mf], bf0[0]);
            MFMA16(acc[mf][1], af0[mf], bf0[1]);
            MFMA16(acc[mf][2], af0[mf], bf0[2]);
            MFMA16(acc[mf][3], af0[mf], bf0[3]);
        }
        __builtin_amdgcn_s_setprio(0);
        __builtin_amdgcn_s_barrier();
        // phase 2
        #pragma unroll
        for (int mf = 0; mf < 4; ++mf) af1[mf] = LDF(ab + (aoffs[mf] ^ 32));
        if (t <= 5) stageB(t + 2, 0);
        __builtin_amdgcn_s_barrier();
        asm volatile("s_waitcnt lgkmcnt(0)" ::: "memory");
        __builtin_amdgcn_sched_barrier(0);
        __builtin_amdgcn_s_setprio(1);
        #pragma unroll
        for (int mf = 0; mf < 4; ++mf) {
            MFMA16(acc[mf][0], af1[mf], bf1[0]);
            MFMA16(acc[mf][1], af1[mf], bf1[1]);
            MFMA16(acc[mf][2], af1[mf], bf1[2]);
            MFMA16(acc[mf][3], af1[mf], bf1[3]);
        }
        __builtin_amdgcn_s_setprio(0);
        __builtin_amdgcn_s_barrier();
        // phase 3
        #pragma unroll
        for (int mf = 4; mf < 8; ++mf) af1[mf] = LDF(ab + (aoffs[mf] ^ 32));
        if (t <= 5) stageB(t + 2, 1);
        __builtin_amdgcn_s_barrier();
        asm volatile("s_waitcnt lgkmcnt(0)" ::: "memory");
        __builtin_amdgcn_sched_barrier(0);
        __builtin_amdgcn_s_setprio(1);
        #pragma unroll
        for (int mf = 4; mf < 8; ++mf) {
            MFMA16(acc[mf][0], af1[mf], bf1[0]);
            MFMA16(acc[mf][1], af1[mf], bf1[1]);
            MFMA16(acc[mf][2], af1[mf], bf1[2]);
            MFMA16(acc[mf][3], af1[mf], bf1[3]);
        }
        __builtin_amdgcn_s_setprio(0);
        if (t <= 5) {
            asm volatile("s_waitcnt vmcnt(4)" ::: "memory");
        } else if (t == 6) {
            asm volatile("s_waitcnt vmcnt(0)" ::: "memory");
        }
        __builtin_amdgcn_sched_barrier(0);
        __builtin_amdgcn_s_barrier();
    }

    #pragma unroll
    for (int mf = 0; mf < 8; ++mf) {
        #pragma unroll
        for (int nf = 0; nf < 4; ++nf) {
            #pragma unroll
            for (int r = 0; r < 4; ++r) {
                long grow = row0 + wm * 128 + mf * 16 + (lane >> 4) * 4 + r;
                int  gcol = col0 + wn * 64 + nf * 16 + fr;
                float v = acc[mf][nf][r];
                if constexpr (OUT_BF16) ((u16*)Dp)[grow * NCOL + gcol] = f2bf(v);
                else                    ((float*)Dp)[grow * NCOL + gcol] = v;
            }
        }
    }
}

// ---------------------------------------------------------------------------
extern "C" void kernel_launch(void* const* d_in, const int* in_sizes, int n_in,
                              void* d_out, int out_size, void* d_ws, size_t ws_size,
                              hipStream_t stream) {
    const float* x    = (const float*)d_in[0];   // (B, N, C) fp32
    const float* Wqkv = (const float*)d_in[1];   // (512, 1536) fp32
    const float* Wout = (const float*)d_in[2];   // (512, 512) fp32
    float* out = (float*)d_out;

    const size_t xc_elems = (size_t)M_ * C_;     // 67.1M u16
    // layout: xb | attn_buf | WqkvT2 | WoutT  (~272 MB total, no aliasing)
    u16* xb       = (u16*)d_ws;
    u16* attn_buf = xb + xc_elems;
    u16* WqkvT2   = attn_buf + xc_elems;
    u16* WoutT    = WqkvT2 + (size_t)1536 * 512;
    if (ws_size < ((size_t)(WoutT + (size_t)512 * 512) - (size_t)d_ws)) return;

    // 1) weight + activation prep
    prep_w2<<<(1536 * 64) / 256, 256, 0, stream>>>(Wqkv, WqkvT2);
    prep_w<<<(512 * 64) / 256, 256, 0, stream>>>(Wout, WoutT, 512);
    prep_x<<<8192, 256, 0, stream>>>(x, xb);

    // 2) fused qkv-GEMM + banded attention (128-row tiles, 2 blocks/CU,
    //    MFMA QK^T epilogue)
    gemm_attn<<<8192, 512, 0, stream>>>(xb, WqkvT2, attn_buf);

    // 3) out = attn @ W_out
    gemm8_k<512, false, true><<<1024, 512, 0, stream>>>(attn_buf, WoutT, (void*)out, 2);
}